// Round 8
// baseline (2625.081 us; speedup 1.0000x reference)
//
#include <hip/hip_runtime.h>
#include <math.h>

// Correctness-critical invariant: kNN sets and eigenvectors must stay
// bit-identical to numpy/LAPACK (f32, contract off). The f64 feature path has
// large rounding slack (absmax 0.0 at threshold 6.7e-5) -> reassociation is
// safe there. W f32->f64 conversion is exact.
#pragma clang fp contract(off)

// ---------------------------------------------------------------------------
__device__ __forceinline__ float f_sign(float a, float b) {
    return (b >= 0.0f) ? fabsf(a) : -fabsf(a);
}

__device__ float slapy2(float x, float y) {
    float xa = fabsf(x), ya = fabsf(y);
    float w = fmaxf(xa, ya), z = fminf(xa, ya);
    if (z == 0.0f) return w;
    float t = z / w;
    return w * sqrtf(1.0f + t * t);
}

__device__ void slartg(float f, float g, float &cs, float &sn, float &r) {
    if (g == 0.0f) { cs = 1.0f; sn = 0.0f; r = f; }
    else if (f == 0.0f) { cs = 0.0f; sn = f_sign(1.0f, g); r = fabsf(g); }
    else {
        float d = sqrtf(f * f + g * g);
        float p = 1.0f / d;
        cs = fabsf(f) * p;
        sn = g * f_sign(p, f);
        r = f_sign(d, f);
    }
}

__device__ void slaev2(float a, float b, float c,
                       float &rt1, float &rt2, float &cs1, float &sn1) {
    float sm = a + c, df = a - c, adf = fabsf(df), tb = b + b, ab = fabsf(tb);
    float acmx, acmn;
    if (fabsf(a) > fabsf(c)) { acmx = a; acmn = c; } else { acmx = c; acmn = a; }
    float rt;
    if (adf > ab) { float t = ab / adf; rt = adf * sqrtf(1.0f + t * t); }
    else if (adf < ab) { float t = adf / ab; rt = ab * sqrtf(1.0f + t * t); }
    else rt = ab * sqrtf(2.0f);
    int sgn1;
    if (sm < 0.0f) { rt1 = 0.5f * (sm - rt); sgn1 = -1; rt2 = (acmx / rt1) * acmn - (b / rt1) * b; }
    else if (sm > 0.0f) { rt1 = 0.5f * (sm + rt); sgn1 = 1; rt2 = (acmx / rt1) * acmn - (b / rt1) * b; }
    else { rt1 = 0.5f * rt; rt2 = -0.5f * rt; sgn1 = 1; }
    float cs; int sgn2;
    if (df >= 0.0f) { cs = df + rt; sgn2 = 1; } else { cs = df - rt; sgn2 = -1; }
    float acs = fabsf(cs);
    if (acs > ab) { float ct = -tb / cs; sn1 = 1.0f / sqrtf(1.0f + ct * ct); cs1 = ct * sn1; }
    else {
        if (ab == 0.0f) { cs1 = 1.0f; sn1 = 0.0f; }
        else { float tn = -cs / tb; cs1 = 1.0f / sqrtf(1.0f + tn * tn); sn1 = tn * cs1; }
    }
    if (sgn1 == sgn2) { float tn = cs1; cs1 = -sn1; sn1 = tn; }
}

// SSTEQR('I', n=3), f32-faithful.
__device__ void ssteqr3(float *d, float *e, float z[3][3]) {
    const int n = 3;
    const float eps = 5.9604644775390625e-08f;
    const float eps2 = eps * eps;
    const float safmin = 1.1754943508222875e-38f;
    for (int i = 0; i < 3; ++i)
        for (int j = 0; j < 3; ++j)
            z[i][j] = (i == j) ? 1.0f : 0.0f;
    const int nmaxit = n * 30;
    int jtot = 0;
    int l1 = 1;
    int l, m, lend;
    float p, g, r, c, s, f, b, rt1, rt2;
    float wc[2], wsn[2];

L10:
    if (l1 > n) goto L160;
    if (l1 > 1) e[l1 - 2] = 0.0f;
    if (l1 <= n - 1) {
        for (m = l1; m <= n - 1; ++m) {
            float tst = fabsf(e[m - 1]);
            if (tst == 0.0f) goto L30;
            if (tst <= (sqrtf(fabsf(d[m - 1])) * sqrtf(fabsf(d[m]))) * eps) {
                e[m - 1] = 0.0f;
                goto L30;
            }
        }
    }
    m = n;
L30:
    l = l1;
    lend = m;
    l1 = m + 1;
    if (lend == l) goto L10;
    {
        float anorm = 0.0f;
        for (int i = l; i <= lend; ++i) anorm = fmaxf(anorm, fabsf(d[i - 1]));
        for (int i = l; i <= lend - 1; ++i) anorm = fmaxf(anorm, fabsf(e[i - 1]));
        if (anorm == 0.0f) goto L10;
    }
    if (fabsf(d[lend - 1]) < fabsf(d[l - 1])) { int t = lend; lend = l; l = t; }

    if (lend > l) {
L40:
        if (l != lend) {
            bool found = false;
            for (m = l; m <= lend - 1; ++m) {
                float tst = e[m - 1] * e[m - 1];
                if (tst <= (eps2 * fabsf(d[m - 1])) * fabsf(d[m]) + safmin) { found = true; break; }
            }
            if (!found) m = lend;
        } else m = lend;
        if (m < lend) e[m - 1] = 0.0f;
        p = d[l - 1];
        if (m == l) goto L80;
        if (m == l + 1) {
            slaev2(d[l - 1], e[l - 1], d[l], rt1, rt2, c, s);
            for (int i = 0; i < n; ++i) {
                float tmp = z[i][l];
                z[i][l]     = c * tmp - s * z[i][l - 1];
                z[i][l - 1] = s * tmp + c * z[i][l - 1];
            }
            d[l - 1] = rt1; d[l] = rt2; e[l - 1] = 0.0f;
            l += 2;
            if (l <= lend) goto L40;
            goto L140;
        }
        if (jtot == nmaxit) goto L140;
        ++jtot;
        g = (d[l] - p) / (2.0f * e[l - 1]);
        r = slapy2(g, 1.0f);
        g = (d[m - 1] - p) + e[l - 1] / (g + f_sign(r, g));
        s = 1.0f; c = 1.0f; p = 0.0f;
        for (int i = m - 1; i >= l; --i) {
            f = s * e[i - 1];
            b = c * e[i - 1];
            slartg(g, f, c, s, r);
            if (i != m - 1) e[i] = r;
            g = d[i] - p;
            r = (d[i - 1] - g) * s + (2.0f * c) * b;
            p = s * r;
            d[i] = g + p;
            g = c * r - b;
            wc[i - 1] = c;
            wsn[i - 1] = -s;
        }
        for (int jj = m - 1; jj >= l; --jj) {
            float ct = wc[jj - 1], st = wsn[jj - 1];
            for (int i = 0; i < n; ++i) {
                float tmp = z[i][jj];
                z[i][jj]     = ct * tmp - st * z[i][jj - 1];
                z[i][jj - 1] = st * tmp + ct * z[i][jj - 1];
            }
        }
        d[l - 1] -= p;
        e[l - 1] = g;
        goto L40;
L80:
        d[l - 1] = p;
        ++l;
        if (l <= lend) goto L40;
        goto L140;
    } else {
L90:
        if (l != lend) {
            bool found = false;
            for (m = l; m >= lend + 1; --m) {
                float tst = e[m - 2] * e[m - 2];
                if (tst <= (eps2 * fabsf(d[m - 1])) * fabsf(d[m - 2]) + safmin) { found = true; break; }
            }
            if (!found) m = lend;
        } else m = lend;
        if (m > lend) e[m - 2] = 0.0f;
        p = d[l - 1];
        if (m == l) goto L130;
        if (m == l - 1) {
            slaev2(d[l - 2], e[l - 2], d[l - 1], rt1, rt2, c, s);
            for (int i = 0; i < n; ++i) {
                float tmp = z[i][l - 1];
                z[i][l - 1] = c * tmp - s * z[i][l - 2];
                z[i][l - 2] = s * tmp + c * z[i][l - 2];
            }
            d[l - 2] = rt1; d[l - 1] = rt2; e[l - 2] = 0.0f;
            l -= 2;
            if (l >= lend) goto L90;
            goto L140;
        }
        if (jtot == nmaxit) goto L140;
        ++jtot;
        g = (d[l - 2] - p) / (2.0f * e[l - 2]);
        r = slapy2(g, 1.0f);
        g = (d[m - 1] - p) + e[l - 2] / (g + f_sign(r, g));
        s = 1.0f; c = 1.0f; p = 0.0f;
        for (int i = m; i <= l - 1; ++i) {
            f = s * e[i - 1];
            b = c * e[i - 1];
            slartg(g, f, c, s, r);
            if (i != m) e[i - 2] = r;
            g = d[i - 1] - p;
            r = (d[i] - g) * s + (2.0f * c) * b;
            p = s * r;
            d[i - 1] = g + p;
            g = c * r - b;
            wc[i - 1] = c;
            wsn[i - 1] = s;
        }
        for (int jj = m; jj <= l - 1; ++jj) {
            float ct = wc[jj - 1], st = wsn[jj - 1];
            for (int i = 0; i < n; ++i) {
                float tmp = z[i][jj];
                z[i][jj]     = ct * tmp - st * z[i][jj - 1];
                z[i][jj - 1] = st * tmp + ct * z[i][jj - 1];
            }
        }
        d[l - 1] -= p;
        e[l - 2] = g;
        goto L90;
L130:
        d[l - 1] = p;
        --l;
        if (l >= lend) goto L90;
        goto L140;
    }
L140:
    if (jtot < nmaxit) goto L10;
L160:
    for (int ii = 2; ii <= n; ++ii) {
        int i = ii - 1, kk = i;
        float pp = d[i - 1];
        for (int j = ii; j <= n; ++j)
            if (d[j - 1] < pp) { kk = j; pp = d[j - 1]; }
        if (kk != i) {
            d[kk - 1] = d[i - 1];
            d[i - 1] = pp;
            for (int row = 0; row < n; ++row) {
                float t2 = z[row][i - 1];
                z[row][i - 1] = z[row][kk - 1];
                z[row][kk - 1] = t2;
            }
        }
    }
}

__device__ void ssyevd3(float a11, float a21, float a31,
                        float a22, float a32, float a33, float V[3][3]) {
    float tau1, v2, e1;
    float alpha = a21;
    float xnorm = fabsf(a31);
    if (xnorm == 0.0f) {
        tau1 = 0.0f; v2 = 0.0f; e1 = a21;
    } else {
        float beta = -f_sign(slapy2(alpha, xnorm), alpha);
        tau1 = (beta - alpha) / beta;
        float t = 1.0f / (alpha - beta);
        v2 = a31 * t;
        e1 = beta;
        float w1 = tau1 * a22;
        float w2 = tau1 * a32;
        float temp2 = a32 * v2;
        w1 = w1 + tau1 * temp2;
        float temp1 = tau1 * v2;
        w2 = w2 + temp1 * a33;
        float dot = w1;
        dot = dot + w2 * v2;
        float alpha2 = (-0.5f * tau1) * dot;
        w1 = w1 + alpha2;
        w2 = w2 + alpha2 * v2;
        a22 = (a22 - w1) - w1;
        a32 = (a32 - v2 * w1) - w2;
        a33 = (a33 - v2 * w2) - w2 * v2;
    }
    float d[3] = { a11, a22, a33 };
    float e[2] = { e1, a32 };
    float z[3][3];
    ssteqr3(d, e, z);
    for (int j = 0; j < 3; ++j) {
        float wj = z[1][j];
        wj = wj + z[2][j] * v2;
        float temp = (-tau1) * wj;
        V[0][j] = z[0][j];
        V[1][j] = z[1][j] + temp;
        V[2][j] = z[2][j] + v2 * temp;
    }
}

// Per-query geometry: r, scale, cov, ssyevd, rotate. Runs on one thread.
__device__ void geom_body(const float *__restrict__ posf, const int *__restrict__ ord,
                          int q, int k, float *__restrict__ rrot) {
    float qx = posf[3 * q], qy = posf[3 * q + 1], qz = posf[3 * q + 2];
    float rx[16], ry[16], rz[16], nrm[16];
    for (int j = 0; j < k; ++j) {
        int s = ord[j];
        rx[j] = posf[3 * s] - qx;
        ry[j] = posf[3 * s + 1] - qy;
        rz[j] = posf[3 * s + 2] - qz;
        float t = rx[j] * rx[j];
        t = t + ry[j] * ry[j];
        t = t + rz[j] * rz[j];
        nrm[j] = sqrtf(t);
    }
    float scale = nrm[0];
    for (int j = 1; j < k; ++j) scale = fmaxf(scale, nrm[j]);
    float sc = scale + 1e-8f;
    for (int j = 0; j < k; ++j) {
        rx[j] = rx[j] / sc;
        ry[j] = ry[j] / sc;
        rz[j] = rz[j] / sc;
    }
    float c00 = 0.f, c01 = 0.f, c02 = 0.f, c11 = 0.f, c12 = 0.f, c22 = 0.f;
    for (int j = 0; j < k; ++j) {
        c00 = c00 + rx[j] * rx[j];
        c01 = c01 + rx[j] * ry[j];
        c02 = c02 + rx[j] * rz[j];
        c11 = c11 + ry[j] * ry[j];
        c12 = c12 + ry[j] * rz[j];
        c22 = c22 + rz[j] * rz[j];
    }
    float fk = (float)k;
    c00 = c00 / fk; c01 = c01 / fk; c02 = c02 / fk;
    c11 = c11 / fk; c12 = c12 / fk; c22 = c22 / fk;
    float V[3][3];
    ssyevd3(c00, c01, c02, c11, c12, c22, V);
    for (int j = 0; j < k; ++j) {
        for (int col = 0; col < 3; ++col) {
            float a = rx[j] * V[0][col];
            a = a + ry[j] * V[1][col];
            a = a + rz[j] * V[2][col];
            rrot[q * 48 + j * 3 + col] = a;
        }
    }
}

// ---------------------------------------------------------------------------

__global__ void prep_kernel(const float *__restrict__ posf, float4 *__restrict__ pos4) {
    int i = blockIdx.x * 256 + threadIdx.x;
    if (i >= 32768) return;
    float x = posf[3 * i], y = posf[3 * i + 1], z = posf[3 * i + 2];
    float t = x * x;
    t = t + y * y;
    t = t + z * z;
    pos4[i] = make_float4(x, y, z, t);
}

// Fused k=16 kNN + geometry. 4 waves/block, 2 candidates/lane/iter,
// wave-global sorted top-16 (lanes 0..15), cached kth, ballot-gated inserts.
// After LDS merge (exact (dist,idx) order), lane 0 runs the eigensolve.
__global__ __launch_bounds__(256) void knng16_kernel(
    const float4 *__restrict__ pos4, const float *__restrict__ posf,
    int S, int *__restrict__ idx_out, float *__restrict__ rrot) {
    __shared__ float md[64];
    __shared__ int mi[64];
    __shared__ int ord[16];
    int q = blockIdx.x;
    int tid = threadIdx.x;
    int lane = tid & 63;
    int w = tid >> 6;
    float4 qp = pos4[q];
    const float FINF = 3.0e38f;
    float ld = FINF;
    int li = 0x7fffffff;
    float kth = FINF;
    for (int base = w * 128; base < S; base += 512) {
        int j0 = base + lane, j1 = base + 64 + lane;
        float d0 = FINF, d1 = FINF;
        if (j0 < S) {
            float4 p = pos4[j0];
            float m = fmaf(qp.x, p.x, 0.0f);
            m = fmaf(qp.y, p.y, m);
            m = fmaf(qp.z, p.z, m);
            d0 = (qp.w + p.w) - 2.0f * m;   // bit-identical reference sgemm form
        }
        if (j1 < S) {
            float4 p = pos4[j1];
            float m = fmaf(qp.x, p.x, 0.0f);
            m = fmaf(qp.y, p.y, m);
            m = fmaf(qp.z, p.z, m);
            d1 = (qp.w + p.w) - 2.0f * m;
        }
        unsigned long long mask = __ballot(d0 < kth);
        while (mask) {
            int src = __ffsll(mask) - 1;
            mask &= mask - 1;
            float dv = __shfl(d0, src);
            int jv = base + src;
            if (dv < kth) {
                bool le = (lane < 16) && (ld <= dv);
                unsigned long long lm = __ballot(le);
                int p2 = __popcll(lm);
                float sd = __shfl_up(ld, 1);
                int si = __shfl_up(li, 1);
                if (lane < 16) {
                    if (lane == p2) { ld = dv; li = jv; }
                    else if (lane > p2) { ld = sd; li = si; }
                }
                kth = __shfl(ld, 15);
            }
        }
        mask = __ballot(d1 < kth);
        while (mask) {
            int src = __ffsll(mask) - 1;
            mask &= mask - 1;
            float dv = __shfl(d1, src);
            int jv = base + 64 + src;
            if (dv < kth) {
                bool le = (lane < 16) && (ld <= dv);
                unsigned long long lm = __ballot(le);
                int p2 = __popcll(lm);
                float sd = __shfl_up(ld, 1);
                int si = __shfl_up(li, 1);
                if (lane < 16) {
                    if (lane == p2) { ld = dv; li = jv; }
                    else if (lane > p2) { ld = sd; li = si; }
                }
                kth = __shfl(ld, 15);
            }
        }
    }
    if (lane < 16) { md[w * 16 + lane] = ld; mi[w * 16 + lane] = li; }
    __syncthreads();
    if (w == 0) {
        float v = md[lane];
        int vi = mi[lane];
        bool used = false;
        for (int r = 0; r < 16; ++r) {
            float cv = used ? FINF : v;
            int ci = used ? 0x7fffffff : vi;
            int cl = lane;
            for (int off = 32; off > 0; off >>= 1) {
                float ov = __shfl_down(cv, off);
                int oi = __shfl_down(ci, off);
                int ol = __shfl_down(cl, off);
                if (ov < cv || (ov == cv && oi < ci)) { cv = ov; ci = oi; cl = ol; }
            }
            ci = __shfl(ci, 0);
            cl = __shfl(cl, 0);
            if (lane == 0) { idx_out[q * 16 + r] = ci; ord[r] = ci; }
            if (lane == cl) used = true;
        }
        if (lane == 0) geom_body(posf, ord, q, 16, rrot);
    }
}

// Fused small-S (S <= 64) kNN + geometry; one wave per query.
__global__ __launch_bounds__(64) void knngs_kernel(
    const float4 *__restrict__ pos4, const float *__restrict__ posf,
    int S, int k, int *__restrict__ idx_out, float *__restrict__ rrot) {
    __shared__ int ord[16];
    int q = blockIdx.x;
    int lane = threadIdx.x;
    float4 qp = pos4[q];
    const float FINF = 3.0e38f;
    float dist = FINF;
    if (lane < S) {
        float4 p = pos4[lane];
        float m = fmaf(qp.x, p.x, 0.0f);
        m = fmaf(qp.y, p.y, m);
        m = fmaf(qp.z, p.z, m);
        dist = (qp.w + p.w) - 2.0f * m;
    }
    bool used = false;
    for (int r = 0; r < k; ++r) {
        float v = used ? FINF : dist;
        int vid = (used || lane >= S) ? 0x7fffffff : lane;
        for (int off = 32; off > 0; off >>= 1) {
            float ov = __shfl_down(v, off);
            int oid = __shfl_down(vid, off);
            if (ov < v || (ov == v && oid < vid)) { v = ov; vid = oid; }
        }
        vid = __shfl(vid, 0);
        if (lane == 0) { idx_out[q * k + r] = vid; ord[r] = vid; }
        if (lane == vid) used = true;
    }
    if (lane == 0) geom_body(posf, ord, q, k, rrot);
}

__device__ __forceinline__ void compute_phi(const float *rrot, int q, int tid,
                                            double phi[45]) {
    double x = (double)rrot[q * 48 + tid * 3 + 0];
    double y = (double)rrot[q * 48 + tid * 3 + 1];
    double z = (double)rrot[q * 48 + tid * 3 + 2];
    double px[5], py[3], pz[3];
    px[0] = 1.0; px[1] = x; px[2] = x * x; px[3] = px[2] * x; px[4] = px[3] * x;
    py[0] = 1.0; py[1] = y; py[2] = y * y;
    pz[0] = 1.0; pz[1] = z; pz[2] = z * z;
#pragma unroll
    for (int n2 = 0; n2 < 5; ++n2)
#pragma unroll
        for (int l2 = 0; l2 < 3; ++l2)
#pragma unroll
            for (int m2 = 0; m2 < 3; ++m2)
                phi[n2 * 9 + l2 * 3 + m2] = (px[n2] * py[l2]) * pz[m2];
}

// Generic per-query fused conv (B0-L1, C=4).
__global__ __launch_bounds__(256) void feat_kernel(
    const float *__restrict__ rrot, const int *__restrict__ idx, int k,
    const double *__restrict__ fin64, const float *__restrict__ fin32, int C,
    const float *__restrict__ W, const float *__restrict__ bias, int O,
    double *__restrict__ fout) {
    __shared__ double phi_sh[16][45];
    __shared__ int idx_sh[16];
    __shared__ double red_sh[256];
    extern __shared__ double dyn[];
    double *nf = dyn;            // [16][C]
    double *t = dyn + 16 * C;    // [9][C]
    int q = blockIdx.x;
    int tid = threadIdx.x;
    int OT = O < 256 ? O : 256;
    int nseg = 256 / OT;
    int o = tid % OT;
    int seg = tid / OT;
    int cseg = C / nseg;
    int c0 = seg * cseg, c1 = c0 + cseg;
    if (tid < k) {
        idx_sh[tid] = idx[q * k + tid];
        double phi[45];
        compute_phi(rrot, q, tid, phi);
#pragma unroll
        for (int b2 = 0; b2 < 45; ++b2) phi_sh[tid][b2] = phi[b2];
    }
    __syncthreads();
    for (int e2 = tid; e2 < k * C; e2 += 256) {
        int j = e2 / C, cc = e2 - j * C;
        size_t src = (size_t)idx_sh[j] * C + cc;
        nf[j * C + cc] = fin32 ? (double)fin32[src] : fin64[src];
    }
    __syncthreads();
    double accp = 0.0;
    for (int ch = 0; ch < 45; ch += 9) {
        for (int e2 = tid; e2 < 9 * C; e2 += 256) {
            int b2 = e2 / C, cc = e2 - b2 * C;
            double a2 = 0.0;
            for (int j = 0; j < k; ++j) a2 = fma(phi_sh[j][ch + b2], nf[j * C + cc], a2);
            t[e2] = a2 / (double)k;
        }
        __syncthreads();
        double a0 = 0.0, a1 = 0.0;
        for (int b2 = 0; b2 < 9; ++b2) {
            const float *wp = W + (size_t)(ch + b2) * C * O + o;
            const double *tp = t + b2 * C;
            int cc = c0;
            for (; cc + 2 <= c1; cc += 2) {
                a0 = fma(tp[cc],     (double)wp[(size_t)cc * O], a0);
                a1 = fma(tp[cc + 1], (double)wp[(size_t)(cc + 1) * O], a1);
            }
            for (; cc < c1; ++cc) a0 = fma(tp[cc], (double)wp[(size_t)cc * O], a0);
        }
        accp += a0 + a1;
        __syncthreads();
    }
    red_sh[tid] = accp;
    __syncthreads();
    if (tid < OT) {
        double v = 0.0;
        for (int s2 = 0; s2 < nseg; ++s2) v += red_sh[tid + s2 * OT];
        v += (double)bias[tid];
        fout[(size_t)q * O + tid] = v > 0.0 ? v : 0.0;
    }
}

// Specialized C=64, O=64, k=16 fused conv (B0-L2), 2 queries per block.
__global__ __launch_bounds__(256) void feat64_kernel(
    const float *__restrict__ rrot, const int *__restrict__ idx,
    const double *__restrict__ fin, const float *__restrict__ W,
    const float *__restrict__ bias, int Q, double *__restrict__ fout) {
    __shared__ double phi_sh[2][16][45];
    __shared__ int idx_sh[2][16];
    __shared__ double nf[2][16][64];
    __shared__ double t[2][9][64];
    __shared__ double red[16][64];
    int q0 = blockIdx.x * 2;
    int nq = (Q - q0) < 2 ? (Q - q0) : 2;
    int tid = threadIdx.x;
    int tx = tid & 15;
    int seg = tid >> 4;
    int o0 = tx * 4;
    int cbase = seg * 4;
    if (tid < 32) {
        int qi = tid >> 4, j = tid & 15;
        int qq = q0 + (qi < nq ? qi : 0);
        idx_sh[qi][j] = idx[qq * 16 + j];
        double phi[45];
        compute_phi(rrot, qq, j, phi);
#pragma unroll
        for (int b2 = 0; b2 < 45; ++b2) phi_sh[qi][j][b2] = phi[b2];
    }
    __syncthreads();
    for (int e2 = tid; e2 < 2 * 16 * 64; e2 += 256) {
        int qi = e2 >> 10, j = (e2 >> 6) & 15, cc = e2 & 63;
        nf[qi][j][cc] = fin[(size_t)idx_sh[qi][j] * 64 + cc];
    }
    __syncthreads();
    double acc[2][4] = {{0.0, 0.0, 0.0, 0.0}, {0.0, 0.0, 0.0, 0.0}};
    for (int ch = 0; ch < 45; ch += 9) {
        for (int e2 = tid; e2 < 2 * 9 * 64; e2 += 256) {
            int qi = e2 / 576, rem = e2 - qi * 576;
            int b2 = rem >> 6, cc = rem & 63;
            double a2 = 0.0;
#pragma unroll
            for (int j = 0; j < 16; ++j) a2 = fma(phi_sh[qi][j][ch + b2], nf[qi][j][cc], a2);
            t[qi][b2][cc] = a2 * 0.0625;
        }
        __syncthreads();
#pragma unroll
        for (int b2 = 0; b2 < 9; ++b2) {
            const float *wrow = W + ((size_t)(ch + b2) * 64 + cbase) * 64 + o0;
#pragma unroll
            for (int i = 0; i < 4; ++i) {
                float4 wv = *(const float4 *)(wrow + (size_t)i * 64);
                double w0 = (double)wv.x, w1 = (double)wv.y;
                double w2 = (double)wv.z, w3 = (double)wv.w;
                double tv0 = t[0][b2][cbase + i];
                double tv1 = t[1][b2][cbase + i];
                acc[0][0] = fma(tv0, w0, acc[0][0]);
                acc[0][1] = fma(tv0, w1, acc[0][1]);
                acc[0][2] = fma(tv0, w2, acc[0][2]);
                acc[0][3] = fma(tv0, w3, acc[0][3]);
                acc[1][0] = fma(tv1, w0, acc[1][0]);
                acc[1][1] = fma(tv1, w1, acc[1][1]);
                acc[1][2] = fma(tv1, w2, acc[1][2]);
                acc[1][3] = fma(tv1, w3, acc[1][3]);
            }
        }
        __syncthreads();
    }
    for (int qi = 0; qi < nq; ++qi) {
        red[seg][o0 + 0] = acc[qi][0];
        red[seg][o0 + 1] = acc[qi][1];
        red[seg][o0 + 2] = acc[qi][2];
        red[seg][o0 + 3] = acc[qi][3];
        __syncthreads();
        if (tid < 64) {
            double v = 0.0;
#pragma unroll
            for (int s2 = 0; s2 < 16; ++s2) v += red[s2][tid];
            v += (double)bias[tid];
            fout[(size_t)(q0 + qi) * 64 + tid] = v > 0.0 ? v : 0.0;
        }
        __syncthreads();
    }
}

// Small-Q layers: one kernel per layer. Grid (Q, 5 basis-chunks of 9).
// Block computes t-chunk (9C) in LDS, multiplies into part[chunk][q][O].
// No tbuf, no atomics, no memset.
__global__ __launch_bounds__(256) void tgemm_kernel(
    const float *__restrict__ rrot, const int *__restrict__ idx, int k,
    const double *__restrict__ fin, int C, const float *__restrict__ W,
    int O, int Q, double *__restrict__ part) {
    __shared__ double phi_sh[16][9];
    __shared__ int idx_sh[16];
    __shared__ double red_sh[256];
    extern __shared__ double dyn[];
    double *nf = dyn;            // [16][C]
    double *t = dyn + 16 * C;    // [9][C]
    int q = blockIdx.x;
    int bch = blockIdx.y * 9;
    int tid = threadIdx.x;
    if (tid < k) {
        idx_sh[tid] = idx[q * k + tid];
        double phi[45];
        compute_phi(rrot, q, tid, phi);
#pragma unroll
        for (int b2 = 0; b2 < 9; ++b2) phi_sh[tid][b2] = phi[bch + b2];
    }
    __syncthreads();
    for (int e2 = tid; e2 < k * C; e2 += 256) {
        int j = e2 / C, cc = e2 - j * C;
        nf[j * C + cc] = fin[(size_t)idx_sh[j] * C + cc];
    }
    __syncthreads();
    for (int e2 = tid; e2 < 9 * C; e2 += 256) {
        int b2 = e2 / C, cc = e2 - b2 * C;
        double a2 = 0.0;
        for (int j = 0; j < k; ++j) a2 = fma(phi_sh[j][b2], nf[j * C + cc], a2);
        t[e2] = a2 / (double)k;
    }
    __syncthreads();
    int K9 = 9 * C;
    double *pslice = part + ((size_t)blockIdx.y * Q + q) * O;
    if (O <= 256) {
        int OT = O;
        int nseg = 256 / OT;
        int o = tid % OT;
        int seg = tid / OT;
        int kseg = K9 / nseg;
        int k0 = seg * kseg, k1 = k0 + kseg;
        const float *wp = W + ((size_t)bch * C + k0) * O + o;
        double a0 = 0.0, a1 = 0.0;
        int kk = k0;
        for (; kk + 2 <= k1; kk += 2) {
            a0 = fma(t[kk], (double)wp[0], a0);
            a1 = fma(t[kk + 1], (double)wp[O], a1);
            wp += 2 * (size_t)O;
        }
        if (kk < k1) a0 = fma(t[kk], (double)wp[0], a0);
        double a = a0 + a1;
        if (nseg > 1) {
            red_sh[tid] = a;
            __syncthreads();
            if (tid < O) {
                double v = 0.0;
                for (int s2 = 0; s2 < nseg; ++s2) v += red_sh[tid + s2 * O];
                pslice[tid] = v;
            }
        } else {
            pslice[o] = a;
        }
    } else {  // O = 512
        for (int ob = 0; ob < O; ob += 256) {
            const float *wp = W + ((size_t)bch * C) * O + ob + tid;
            double a0 = 0.0, a1 = 0.0;
            for (int kk = 0; kk + 2 <= K9; kk += 2) {
                a0 = fma(t[kk], (double)wp[0], a0);
                a1 = fma(t[kk + 1], (double)wp[O], a1);
                wp += 2 * (size_t)O;
            }
            pslice[ob + tid] = a0 + a1;
        }
    }
}

// out = relu(sum_{c<5} part[c][q][o] + bias[o])
__global__ void finalize5_kernel(const double *__restrict__ part,
                                 const float *__restrict__ bias,
                                 int Q, int O, double *__restrict__ fout) {
    int i = blockIdx.x * 256 + threadIdx.x;
    if (i >= Q * O) return;
    int o = i % O;
    double v = 0.0;
    for (int c = 0; c < 5; ++c) v += part[(size_t)c * Q * O + i];
    v += (double)bias[o];
    fout[i] = v > 0.0 ? v : 0.0;
}

__global__ void resid0_kernel(const float *__restrict__ chanf, const float *__restrict__ p,
                              const double *__restrict__ x, double *__restrict__ fout) {
    int i = blockIdx.x * 256 + threadIdx.x;
    if (i >= 2435 * 64) return;
    int q = i >> 6, o = i & 63;
    const float *f = chanf + 4 * q;
    float c = fmaf(f[0], p[o], 0.0f);
    c = fmaf(f[1], p[64 + o], c);
    c = fmaf(f[2], p[128 + o], c);
    c = fmaf(f[3], p[192 + o], c);
    double v = x[i] + (double)c;
    fout[i] = v > 0.0 ? v : 0.0;
}

__global__ void resid64_kernel(const double *__restrict__ fin, int Cin,
                               const float *__restrict__ p, const double *__restrict__ x,
                               int Q, int Cout, double *__restrict__ fout) {
    int i = blockIdx.x * blockDim.x + threadIdx.x;
    if (i >= Q * Cout) return;
    int q = i / Cout, o = i - q * Cout;
    double acc = 0.0;
    for (int c = 0; c < Cin; ++c) acc = fma(fin[q * Cin + c], (double)p[c * Cout + o], acc);
    double v = x[i] + acc;
    fout[i] = v > 0.0 ? v : 0.0;
}

__global__ void head_kernel(const double *__restrict__ feat, const float *__restrict__ hw,
                            const float *__restrict__ hb, float *__restrict__ out) {
    if (threadIdx.x == 0 && blockIdx.x == 0) {
        double acc = 0.0;
        for (int c = 0; c < 512; ++c) acc = fma(feat[c], (double)hw[c], acc);
        out[0] = (float)(acc + (double)hb[0]);
    }
}

// ---------------------------------------------------------------------------

extern "C" void kernel_launch(void *const *d_in, const int *in_sizes, int n_in,
                              void *d_out, int out_size, void *d_ws, size_t ws_size,
                              hipStream_t stream) {
    (void)in_sizes; (void)n_in; (void)out_size;

    const float *posf = (const float *)d_in[0];
    const float *chanf = (const float *)d_in[1];
    const float *W[8], *B[8];
    for (int li = 1; li <= 7; ++li) {
        W[li] = (const float *)d_in[2 + 2 * (li - 1)];
        B[li] = (const float *)d_in[3 + 2 * (li - 1)];
    }
    const float *P[5];
    for (int bi = 1; bi <= 4; ++bi) P[bi] = (const float *)d_in[15 + bi];
    const float *hw = (const float *)d_in[20];
    const float *hb = (const float *)d_in[21];

    // workspace layout (bytes)
    char *wsb = (char *)d_ws;
    double *B1   = (double *)(wsb + 0);            // 2435*64 f64 = 1,246,720
    double *B2   = (double *)(wsb + 1246720);
    double *B3   = (double *)(wsb + 2493440);
    float *rrot  = (float *)(wsb + 3740160);       // 2435*48 f32 = 467,520
    int *idx     = (int *)(wsb + 4207680);         // 2435*16 = 155,840
    float4 *pos4 = (float4 *)(wsb + 4363520);      // 32768*16 = 524,288
    double *part = (double *)(wsb + 4887808);      // 5*181*128*8 = 926,080 max
    if (ws_size < 5813888) return;

    prep_kernel<<<128, 256, 0, stream>>>(posf, pos4);

    auto knng = [&](int Q, int S, int k) {
        if (S <= 64)
            knngs_kernel<<<Q, 64, 0, stream>>>(pos4, posf, S, k, idx, rrot);
        else
            knng16_kernel<<<Q, 256, 0, stream>>>(pos4, posf, S, idx, rrot);
    };

    // fused per-query path (B0-L1)
    auto conv = [&](int Q, int S, int k, const double *fin64, const float *fin32, int C,
                    const float *w, const float *bias, int O, double *fout) {
        knng(Q, S, k);
        size_t dyn = (size_t)(16 + 9) * C * sizeof(double);
        feat_kernel<<<Q, 256, dyn, stream>>>(rrot, idx, k, fin64, fin32, C, w, bias, O, fout);
    };

    // specialized C=64/O=64 path (B0-L2)
    auto conv64 = [&](int Q, int S, const double *fin, const float *w,
                      const float *bias, double *fout) {
        knng(Q, S, 16);
        feat64_kernel<<<(Q + 1) / 2, 256, 0, stream>>>(rrot, idx, fin, w, bias, Q, fout);
    };

    // small-Q path: knng + tgemm(Q,5) + finalize5
    auto conv2 = [&](int Q, int S, int k, const double *fin, int C,
                     const float *w, const float *bias, int O, double *fout) {
        knng(Q, S, k);
        dim3 g(Q, 5);
        size_t dyn = (size_t)(16 + 9) * C * sizeof(double);
        tgemm_kernel<<<g, 256, dyn, stream>>>(rrot, idx, k, fin, C, w, O, Q, part);
        finalize5_kernel<<<(Q * O + 255) / 256, 256, 0, stream>>>(part, bias, Q, O, fout);
    };

    // Block 0 (Q=2435)
    conv(2435, 32768, 16, nullptr, chanf, 4, W[1], B[1], 64, B1);
    conv64(2435, 2435, B1, W[2], B[2], B2);
    resid0_kernel<<<(2435 * 64 + 255) / 256, 256, 0, stream>>>(chanf, P[1], B2, B3);
    // Block 1 (Q=181)
    conv2(181, 2435, 16, B3, 64, W[3], B[3], 128, B1);
    conv2(181, 181, 16, B1, 128, W[4], B[4], 128, B2);
    resid64_kernel<<<(181 * 128 + 255) / 256, 256, 0, stream>>>(B3, 64, P[2], B2, 181, 128, B1);
    // Block 2 (Q=13)
    conv2(13, 181, 16, B1, 128, W[5], B[5], 256, B2);
    conv2(13, 13, 13, B2, 256, W[6], B[6], 256, B3);
    resid64_kernel<<<(13 * 256 + 255) / 256, 256, 0, stream>>>(B1, 128, P[3], B3, 13, 256, B2);
    // Block 3 (Q=1)
    conv2(1, 13, 13, B2, 256, W[7], B[7], 512, B1);
    resid64_kernel<<<(1 * 512 + 255) / 256, 256, 0, stream>>>(B2, 256, P[4], B1, 1, 512, B3);

    head_kernel<<<1, 64, 0, stream>>>(B3, hw, hb, (float *)d_out);
}

// Round 9
// 1301.923 us; speedup vs baseline: 2.0163x; 2.0163x over previous
//
#include <hip/hip_runtime.h>
#include <math.h>

// Correctness-critical invariant: kNN sets and eigenvectors must stay
// bit-identical to numpy/LAPACK (f32, contract off). The f64 feature path has
// large rounding slack (absmax 0.0 at threshold 6.7e-5) -> reassociation and
// f64 atomics are safe there. W f32->f64 conversion is exact.
//
// LESSON (r8): small-Q layers NEED the K-split grid dimension. tgemm fused it
// away -> B3-L7 ran on 5 blocks at 950us. Keep gemm_kernel's ksplit.
#pragma clang fp contract(off)

// ---------------------------------------------------------------------------
__device__ __forceinline__ float f_sign(float a, float b) {
    return (b >= 0.0f) ? fabsf(a) : -fabsf(a);
}

__device__ float slapy2(float x, float y) {
    float xa = fabsf(x), ya = fabsf(y);
    float w = fmaxf(xa, ya), z = fminf(xa, ya);
    if (z == 0.0f) return w;
    float t = z / w;
    return w * sqrtf(1.0f + t * t);
}

__device__ void slartg(float f, float g, float &cs, float &sn, float &r) {
    if (g == 0.0f) { cs = 1.0f; sn = 0.0f; r = f; }
    else if (f == 0.0f) { cs = 0.0f; sn = f_sign(1.0f, g); r = fabsf(g); }
    else {
        float d = sqrtf(f * f + g * g);
        float p = 1.0f / d;
        cs = fabsf(f) * p;
        sn = g * f_sign(p, f);
        r = f_sign(d, f);
    }
}

__device__ void slaev2(float a, float b, float c,
                       float &rt1, float &rt2, float &cs1, float &sn1) {
    float sm = a + c, df = a - c, adf = fabsf(df), tb = b + b, ab = fabsf(tb);
    float acmx, acmn;
    if (fabsf(a) > fabsf(c)) { acmx = a; acmn = c; } else { acmx = c; acmn = a; }
    float rt;
    if (adf > ab) { float t = ab / adf; rt = adf * sqrtf(1.0f + t * t); }
    else if (adf < ab) { float t = adf / ab; rt = ab * sqrtf(1.0f + t * t); }
    else rt = ab * sqrtf(2.0f);
    int sgn1;
    if (sm < 0.0f) { rt1 = 0.5f * (sm - rt); sgn1 = -1; rt2 = (acmx / rt1) * acmn - (b / rt1) * b; }
    else if (sm > 0.0f) { rt1 = 0.5f * (sm + rt); sgn1 = 1; rt2 = (acmx / rt1) * acmn - (b / rt1) * b; }
    else { rt1 = 0.5f * rt; rt2 = -0.5f * rt; sgn1 = 1; }
    float cs; int sgn2;
    if (df >= 0.0f) { cs = df + rt; sgn2 = 1; } else { cs = df - rt; sgn2 = -1; }
    float acs = fabsf(cs);
    if (acs > ab) { float ct = -tb / cs; sn1 = 1.0f / sqrtf(1.0f + ct * ct); cs1 = ct * sn1; }
    else {
        if (ab == 0.0f) { cs1 = 1.0f; sn1 = 0.0f; }
        else { float tn = -cs / tb; cs1 = 1.0f / sqrtf(1.0f + tn * tn); sn1 = tn * cs1; }
    }
    if (sgn1 == sgn2) { float tn = cs1; cs1 = -sn1; sn1 = tn; }
}

// SSTEQR('I', n=3), f32-faithful.
__device__ void ssteqr3(float *d, float *e, float z[3][3]) {
    const int n = 3;
    const float eps = 5.9604644775390625e-08f;
    const float eps2 = eps * eps;
    const float safmin = 1.1754943508222875e-38f;
    for (int i = 0; i < 3; ++i)
        for (int j = 0; j < 3; ++j)
            z[i][j] = (i == j) ? 1.0f : 0.0f;
    const int nmaxit = n * 30;
    int jtot = 0;
    int l1 = 1;
    int l, m, lend;
    float p, g, r, c, s, f, b, rt1, rt2;
    float wc[2], wsn[2];

L10:
    if (l1 > n) goto L160;
    if (l1 > 1) e[l1 - 2] = 0.0f;
    if (l1 <= n - 1) {
        for (m = l1; m <= n - 1; ++m) {
            float tst = fabsf(e[m - 1]);
            if (tst == 0.0f) goto L30;
            if (tst <= (sqrtf(fabsf(d[m - 1])) * sqrtf(fabsf(d[m]))) * eps) {
                e[m - 1] = 0.0f;
                goto L30;
            }
        }
    }
    m = n;
L30:
    l = l1;
    lend = m;
    l1 = m + 1;
    if (lend == l) goto L10;
    {
        float anorm = 0.0f;
        for (int i = l; i <= lend; ++i) anorm = fmaxf(anorm, fabsf(d[i - 1]));
        for (int i = l; i <= lend - 1; ++i) anorm = fmaxf(anorm, fabsf(e[i - 1]));
        if (anorm == 0.0f) goto L10;
    }
    if (fabsf(d[lend - 1]) < fabsf(d[l - 1])) { int t = lend; lend = l; l = t; }

    if (lend > l) {
L40:
        if (l != lend) {
            bool found = false;
            for (m = l; m <= lend - 1; ++m) {
                float tst = e[m - 1] * e[m - 1];
                if (tst <= (eps2 * fabsf(d[m - 1])) * fabsf(d[m]) + safmin) { found = true; break; }
            }
            if (!found) m = lend;
        } else m = lend;
        if (m < lend) e[m - 1] = 0.0f;
        p = d[l - 1];
        if (m == l) goto L80;
        if (m == l + 1) {
            slaev2(d[l - 1], e[l - 1], d[l], rt1, rt2, c, s);
            for (int i = 0; i < n; ++i) {
                float tmp = z[i][l];
                z[i][l]     = c * tmp - s * z[i][l - 1];
                z[i][l - 1] = s * tmp + c * z[i][l - 1];
            }
            d[l - 1] = rt1; d[l] = rt2; e[l - 1] = 0.0f;
            l += 2;
            if (l <= lend) goto L40;
            goto L140;
        }
        if (jtot == nmaxit) goto L140;
        ++jtot;
        g = (d[l] - p) / (2.0f * e[l - 1]);
        r = slapy2(g, 1.0f);
        g = (d[m - 1] - p) + e[l - 1] / (g + f_sign(r, g));
        s = 1.0f; c = 1.0f; p = 0.0f;
        for (int i = m - 1; i >= l; --i) {
            f = s * e[i - 1];
            b = c * e[i - 1];
            slartg(g, f, c, s, r);
            if (i != m - 1) e[i] = r;
            g = d[i] - p;
            r = (d[i - 1] - g) * s + (2.0f * c) * b;
            p = s * r;
            d[i] = g + p;
            g = c * r - b;
            wc[i - 1] = c;
            wsn[i - 1] = -s;
        }
        for (int jj = m - 1; jj >= l; --jj) {
            float ct = wc[jj - 1], st = wsn[jj - 1];
            for (int i = 0; i < n; ++i) {
                float tmp = z[i][jj];
                z[i][jj]     = ct * tmp - st * z[i][jj - 1];
                z[i][jj - 1] = st * tmp + ct * z[i][jj - 1];
            }
        }
        d[l - 1] -= p;
        e[l - 1] = g;
        goto L40;
L80:
        d[l - 1] = p;
        ++l;
        if (l <= lend) goto L40;
        goto L140;
    } else {
L90:
        if (l != lend) {
            bool found = false;
            for (m = l; m >= lend + 1; --m) {
                float tst = e[m - 2] * e[m - 2];
                if (tst <= (eps2 * fabsf(d[m - 1])) * fabsf(d[m - 2]) + safmin) { found = true; break; }
            }
            if (!found) m = lend;
        } else m = lend;
        if (m > lend) e[m - 2] = 0.0f;
        p = d[l - 1];
        if (m == l) goto L130;
        if (m == l - 1) {
            slaev2(d[l - 2], e[l - 2], d[l - 1], rt1, rt2, c, s);
            for (int i = 0; i < n; ++i) {
                float tmp = z[i][l - 1];
                z[i][l - 1] = c * tmp - s * z[i][l - 2];
                z[i][l - 2] = s * tmp + c * z[i][l - 2];
            }
            d[l - 2] = rt1; d[l - 1] = rt2; e[l - 2] = 0.0f;
            l -= 2;
            if (l >= lend) goto L90;
            goto L140;
        }
        if (jtot == nmaxit) goto L140;
        ++jtot;
        g = (d[l - 2] - p) / (2.0f * e[l - 2]);
        r = slapy2(g, 1.0f);
        g = (d[m - 1] - p) + e[l - 2] / (g + f_sign(r, g));
        s = 1.0f; c = 1.0f; p = 0.0f;
        for (int i = m; i <= l - 1; ++i) {
            f = s * e[i - 1];
            b = c * e[i - 1];
            slartg(g, f, c, s, r);
            if (i != m) e[i - 2] = r;
            g = d[i - 1] - p;
            r = (d[i] - g) * s + (2.0f * c) * b;
            p = s * r;
            d[i - 1] = g + p;
            g = c * r - b;
            wc[i - 1] = c;
            wsn[i - 1] = s;
        }
        for (int jj = m; jj <= l - 1; ++jj) {
            float ct = wc[jj - 1], st = wsn[jj - 1];
            for (int i = 0; i < n; ++i) {
                float tmp = z[i][jj];
                z[i][jj]     = ct * tmp - st * z[i][jj - 1];
                z[i][jj - 1] = st * tmp + ct * z[i][jj - 1];
            }
        }
        d[l - 1] -= p;
        e[l - 2] = g;
        goto L90;
L130:
        d[l - 1] = p;
        --l;
        if (l >= lend) goto L90;
        goto L140;
    }
L140:
    if (jtot < nmaxit) goto L10;
L160:
    for (int ii = 2; ii <= n; ++ii) {
        int i = ii - 1, kk = i;
        float pp = d[i - 1];
        for (int j = ii; j <= n; ++j)
            if (d[j - 1] < pp) { kk = j; pp = d[j - 1]; }
        if (kk != i) {
            d[kk - 1] = d[i - 1];
            d[i - 1] = pp;
            for (int row = 0; row < n; ++row) {
                float t2 = z[row][i - 1];
                z[row][i - 1] = z[row][kk - 1];
                z[row][kk - 1] = t2;
            }
        }
    }
}

__device__ void ssyevd3(float a11, float a21, float a31,
                        float a22, float a32, float a33, float V[3][3]) {
    float tau1, v2, e1;
    float alpha = a21;
    float xnorm = fabsf(a31);
    if (xnorm == 0.0f) {
        tau1 = 0.0f; v2 = 0.0f; e1 = a21;
    } else {
        float beta = -f_sign(slapy2(alpha, xnorm), alpha);
        tau1 = (beta - alpha) / beta;
        float t = 1.0f / (alpha - beta);
        v2 = a31 * t;
        e1 = beta;
        float w1 = tau1 * a22;
        float w2 = tau1 * a32;
        float temp2 = a32 * v2;
        w1 = w1 + tau1 * temp2;
        float temp1 = tau1 * v2;
        w2 = w2 + temp1 * a33;
        float dot = w1;
        dot = dot + w2 * v2;
        float alpha2 = (-0.5f * tau1) * dot;
        w1 = w1 + alpha2;
        w2 = w2 + alpha2 * v2;
        a22 = (a22 - w1) - w1;
        a32 = (a32 - v2 * w1) - w2;
        a33 = (a33 - v2 * w2) - w2 * v2;
    }
    float d[3] = { a11, a22, a33 };
    float e[2] = { e1, a32 };
    float z[3][3];
    ssteqr3(d, e, z);
    for (int j = 0; j < 3; ++j) {
        float wj = z[1][j];
        wj = wj + z[2][j] * v2;
        float temp = (-tau1) * wj;
        V[0][j] = z[0][j];
        V[1][j] = z[1][j] + temp;
        V[2][j] = z[2][j] + v2 * temp;
    }
}

// Per-query geometry: r, scale, cov, ssyevd, rotate. Runs on one thread.
__device__ void geom_body(const float *__restrict__ posf, const int *__restrict__ ord,
                          int q, int k, float *__restrict__ rrot) {
    float qx = posf[3 * q], qy = posf[3 * q + 1], qz = posf[3 * q + 2];
    float rx[16], ry[16], rz[16], nrm[16];
    for (int j = 0; j < k; ++j) {
        int s = ord[j];
        rx[j] = posf[3 * s] - qx;
        ry[j] = posf[3 * s + 1] - qy;
        rz[j] = posf[3 * s + 2] - qz;
        float t = rx[j] * rx[j];
        t = t + ry[j] * ry[j];
        t = t + rz[j] * rz[j];
        nrm[j] = sqrtf(t);
    }
    float scale = nrm[0];
    for (int j = 1; j < k; ++j) scale = fmaxf(scale, nrm[j]);
    float sc = scale + 1e-8f;
    for (int j = 0; j < k; ++j) {
        rx[j] = rx[j] / sc;
        ry[j] = ry[j] / sc;
        rz[j] = rz[j] / sc;
    }
    float c00 = 0.f, c01 = 0.f, c02 = 0.f, c11 = 0.f, c12 = 0.f, c22 = 0.f;
    for (int j = 0; j < k; ++j) {
        c00 = c00 + rx[j] * rx[j];
        c01 = c01 + rx[j] * ry[j];
        c02 = c02 + rx[j] * rz[j];
        c11 = c11 + ry[j] * ry[j];
        c12 = c12 + ry[j] * rz[j];
        c22 = c22 + rz[j] * rz[j];
    }
    float fk = (float)k;
    c00 = c00 / fk; c01 = c01 / fk; c02 = c02 / fk;
    c11 = c11 / fk; c12 = c12 / fk; c22 = c22 / fk;
    float V[3][3];
    ssyevd3(c00, c01, c02, c11, c12, c22, V);
    for (int j = 0; j < k; ++j) {
        for (int col = 0; col < 3; ++col) {
            float a = rx[j] * V[0][col];
            a = a + ry[j] * V[1][col];
            a = a + rz[j] * V[2][col];
            rrot[q * 48 + j * 3 + col] = a;
        }
    }
}

// ---------------------------------------------------------------------------

__global__ void prep_kernel(const float *__restrict__ posf, float4 *__restrict__ pos4) {
    int i = blockIdx.x * 256 + threadIdx.x;
    if (i >= 32768) return;
    float x = posf[3 * i], y = posf[3 * i + 1], z = posf[3 * i + 2];
    float t = x * x;
    t = t + y * y;
    t = t + z * z;
    pos4[i] = make_float4(x, y, z, t);
}

// Fused k=16 kNN + geometry. 4 waves/block, 2 candidates/lane/iter,
// wave-global sorted top-16 (lanes 0..15), cached kth, ballot-gated inserts.
// After LDS merge (exact (dist,idx) order), lane 0 runs the eigensolve.
__global__ __launch_bounds__(256) void knng16_kernel(
    const float4 *__restrict__ pos4, const float *__restrict__ posf,
    int S, int *__restrict__ idx_out, float *__restrict__ rrot) {
    __shared__ float md[64];
    __shared__ int mi[64];
    __shared__ int ord[16];
    int q = blockIdx.x;
    int tid = threadIdx.x;
    int lane = tid & 63;
    int w = tid >> 6;
    float4 qp = pos4[q];
    const float FINF = 3.0e38f;
    float ld = FINF;
    int li = 0x7fffffff;
    float kth = FINF;
    for (int base = w * 128; base < S; base += 512) {
        int j0 = base + lane, j1 = base + 64 + lane;
        float d0 = FINF, d1 = FINF;
        if (j0 < S) {
            float4 p = pos4[j0];
            float m = fmaf(qp.x, p.x, 0.0f);
            m = fmaf(qp.y, p.y, m);
            m = fmaf(qp.z, p.z, m);
            d0 = (qp.w + p.w) - 2.0f * m;   // bit-identical reference sgemm form
        }
        if (j1 < S) {
            float4 p = pos4[j1];
            float m = fmaf(qp.x, p.x, 0.0f);
            m = fmaf(qp.y, p.y, m);
            m = fmaf(qp.z, p.z, m);
            d1 = (qp.w + p.w) - 2.0f * m;
        }
        unsigned long long mask = __ballot(d0 < kth);
        while (mask) {
            int src = __ffsll(mask) - 1;
            mask &= mask - 1;
            float dv = __shfl(d0, src);
            int jv = base + src;
            if (dv < kth) {
                bool le = (lane < 16) && (ld <= dv);
                unsigned long long lm = __ballot(le);
                int p2 = __popcll(lm);
                float sd = __shfl_up(ld, 1);
                int si = __shfl_up(li, 1);
                if (lane < 16) {
                    if (lane == p2) { ld = dv; li = jv; }
                    else if (lane > p2) { ld = sd; li = si; }
                }
                kth = __shfl(ld, 15);
            }
        }
        mask = __ballot(d1 < kth);
        while (mask) {
            int src = __ffsll(mask) - 1;
            mask &= mask - 1;
            float dv = __shfl(d1, src);
            int jv = base + 64 + src;
            if (dv < kth) {
                bool le = (lane < 16) && (ld <= dv);
                unsigned long long lm = __ballot(le);
                int p2 = __popcll(lm);
                float sd = __shfl_up(ld, 1);
                int si = __shfl_up(li, 1);
                if (lane < 16) {
                    if (lane == p2) { ld = dv; li = jv; }
                    else if (lane > p2) { ld = sd; li = si; }
                }
                kth = __shfl(ld, 15);
            }
        }
    }
    if (lane < 16) { md[w * 16 + lane] = ld; mi[w * 16 + lane] = li; }
    __syncthreads();
    if (w == 0) {
        float v = md[lane];
        int vi = mi[lane];
        bool used = false;
        for (int r = 0; r < 16; ++r) {
            float cv = used ? FINF : v;
            int ci = used ? 0x7fffffff : vi;
            int cl = lane;
            for (int off = 32; off > 0; off >>= 1) {
                float ov = __shfl_down(cv, off);
                int oi = __shfl_down(ci, off);
                int ol = __shfl_down(cl, off);
                if (ov < cv || (ov == cv && oi < ci)) { cv = ov; ci = oi; cl = ol; }
            }
            ci = __shfl(ci, 0);
            cl = __shfl(cl, 0);
            if (lane == 0) { idx_out[q * 16 + r] = ci; ord[r] = ci; }
            if (lane == cl) used = true;
        }
        if (lane == 0) geom_body(posf, ord, q, 16, rrot);
    }
}

// Fused small-S (S <= 64) kNN + geometry; one wave per query.
__global__ __launch_bounds__(64) void knngs_kernel(
    const float4 *__restrict__ pos4, const float *__restrict__ posf,
    int S, int k, int *__restrict__ idx_out, float *__restrict__ rrot) {
    __shared__ int ord[16];
    int q = blockIdx.x;
    int lane = threadIdx.x;
    float4 qp = pos4[q];
    const float FINF = 3.0e38f;
    float dist = FINF;
    if (lane < S) {
        float4 p = pos4[lane];
        float m = fmaf(qp.x, p.x, 0.0f);
        m = fmaf(qp.y, p.y, m);
        m = fmaf(qp.z, p.z, m);
        dist = (qp.w + p.w) - 2.0f * m;
    }
    bool used = false;
    for (int r = 0; r < k; ++r) {
        float v = used ? FINF : dist;
        int vid = (used || lane >= S) ? 0x7fffffff : lane;
        for (int off = 32; off > 0; off >>= 1) {
            float ov = __shfl_down(v, off);
            int oid = __shfl_down(vid, off);
            if (ov < v || (ov == v && oid < vid)) { v = ov; vid = oid; }
        }
        vid = __shfl(vid, 0);
        if (lane == 0) { idx_out[q * k + r] = vid; ord[r] = vid; }
        if (lane == vid) used = true;
    }
    if (lane == 0) geom_body(posf, ord, q, k, rrot);
}

__device__ __forceinline__ void compute_phi(const float *rrot, int q, int tid,
                                            double phi[45]) {
    double x = (double)rrot[q * 48 + tid * 3 + 0];
    double y = (double)rrot[q * 48 + tid * 3 + 1];
    double z = (double)rrot[q * 48 + tid * 3 + 2];
    double px[5], py[3], pz[3];
    px[0] = 1.0; px[1] = x; px[2] = x * x; px[3] = px[2] * x; px[4] = px[3] * x;
    py[0] = 1.0; py[1] = y; py[2] = y * y;
    pz[0] = 1.0; pz[1] = z; pz[2] = z * z;
#pragma unroll
    for (int n2 = 0; n2 < 5; ++n2)
#pragma unroll
        for (int l2 = 0; l2 < 3; ++l2)
#pragma unroll
            for (int m2 = 0; m2 < 3; ++m2)
                phi[n2 * 9 + l2 * 3 + m2] = (px[n2] * py[l2]) * pz[m2];
}

// Generic per-query fused conv (B0-L1, C=4).
__global__ __launch_bounds__(256) void feat_kernel(
    const float *__restrict__ rrot, const int *__restrict__ idx, int k,
    const double *__restrict__ fin64, const float *__restrict__ fin32, int C,
    const float *__restrict__ W, const float *__restrict__ bias, int O,
    double *__restrict__ fout) {
    __shared__ double phi_sh[16][45];
    __shared__ int idx_sh[16];
    __shared__ double red_sh[256];
    extern __shared__ double dyn[];
    double *nf = dyn;            // [16][C]
    double *t = dyn + 16 * C;    // [9][C]
    int q = blockIdx.x;
    int tid = threadIdx.x;
    int OT = O < 256 ? O : 256;
    int nseg = 256 / OT;
    int o = tid % OT;
    int seg = tid / OT;
    int cseg = C / nseg;
    int c0 = seg * cseg, c1 = c0 + cseg;
    if (tid < k) {
        idx_sh[tid] = idx[q * k + tid];
        double phi[45];
        compute_phi(rrot, q, tid, phi);
#pragma unroll
        for (int b2 = 0; b2 < 45; ++b2) phi_sh[tid][b2] = phi[b2];
    }
    __syncthreads();
    for (int e2 = tid; e2 < k * C; e2 += 256) {
        int j = e2 / C, cc = e2 - j * C;
        size_t src = (size_t)idx_sh[j] * C + cc;
        nf[j * C + cc] = fin32 ? (double)fin32[src] : fin64[src];
    }
    __syncthreads();
    double accp = 0.0;
    for (int ch = 0; ch < 45; ch += 9) {
        for (int e2 = tid; e2 < 9 * C; e2 += 256) {
            int b2 = e2 / C, cc = e2 - b2 * C;
            double a2 = 0.0;
            for (int j = 0; j < k; ++j) a2 = fma(phi_sh[j][ch + b2], nf[j * C + cc], a2);
            t[e2] = a2 / (double)k;
        }
        __syncthreads();
        double a0 = 0.0, a1 = 0.0;
        for (int b2 = 0; b2 < 9; ++b2) {
            const float *wp = W + (size_t)(ch + b2) * C * O + o;
            const double *tp = t + b2 * C;
            int cc = c0;
            for (; cc + 2 <= c1; cc += 2) {
                a0 = fma(tp[cc],     (double)wp[(size_t)cc * O], a0);
                a1 = fma(tp[cc + 1], (double)wp[(size_t)(cc + 1) * O], a1);
            }
            for (; cc < c1; ++cc) a0 = fma(tp[cc], (double)wp[(size_t)cc * O], a0);
        }
        accp += a0 + a1;
        __syncthreads();
    }
    red_sh[tid] = accp;
    __syncthreads();
    if (tid < OT) {
        double v = 0.0;
        for (int s2 = 0; s2 < nseg; ++s2) v += red_sh[tid + s2 * OT];
        v += (double)bias[tid];
        fout[(size_t)q * O + tid] = v > 0.0 ? v : 0.0;
    }
}

// Specialized C=64, O=64, k=16 fused conv (B0-L2), 2 queries per block.
__global__ __launch_bounds__(256) void feat64_kernel(
    const float *__restrict__ rrot, const int *__restrict__ idx,
    const double *__restrict__ fin, const float *__restrict__ W,
    const float *__restrict__ bias, int Q, double *__restrict__ fout) {
    __shared__ double phi_sh[2][16][45];
    __shared__ int idx_sh[2][16];
    __shared__ double nf[2][16][64];
    __shared__ double t[2][9][64];
    __shared__ double red[16][64];
    int q0 = blockIdx.x * 2;
    int nq = (Q - q0) < 2 ? (Q - q0) : 2;
    int tid = threadIdx.x;
    int tx = tid & 15;
    int seg = tid >> 4;
    int o0 = tx * 4;
    int cbase = seg * 4;
    if (tid < 32) {
        int qi = tid >> 4, j = tid & 15;
        int qq = q0 + (qi < nq ? qi : 0);
        idx_sh[qi][j] = idx[qq * 16 + j];
        double phi[45];
        compute_phi(rrot, qq, j, phi);
#pragma unroll
        for (int b2 = 0; b2 < 45; ++b2) phi_sh[qi][j][b2] = phi[b2];
    }
    __syncthreads();
    for (int e2 = tid; e2 < 2 * 16 * 64; e2 += 256) {
        int qi = e2 >> 10, j = (e2 >> 6) & 15, cc = e2 & 63;
        nf[qi][j][cc] = fin[(size_t)idx_sh[qi][j] * 64 + cc];
    }
    __syncthreads();
    double acc[2][4] = {{0.0, 0.0, 0.0, 0.0}, {0.0, 0.0, 0.0, 0.0}};
    for (int ch = 0; ch < 45; ch += 9) {
        for (int e2 = tid; e2 < 2 * 9 * 64; e2 += 256) {
            int qi = e2 / 576, rem = e2 - qi * 576;
            int b2 = rem >> 6, cc = rem & 63;
            double a2 = 0.0;
#pragma unroll
            for (int j = 0; j < 16; ++j) a2 = fma(phi_sh[qi][j][ch + b2], nf[qi][j][cc], a2);
            t[qi][b2][cc] = a2 * 0.0625;
        }
        __syncthreads();
#pragma unroll
        for (int b2 = 0; b2 < 9; ++b2) {
            const float *wrow = W + ((size_t)(ch + b2) * 64 + cbase) * 64 + o0;
#pragma unroll
            for (int i = 0; i < 4; ++i) {
                float4 wv = *(const float4 *)(wrow + (size_t)i * 64);
                double w0 = (double)wv.x, w1 = (double)wv.y;
                double w2 = (double)wv.z, w3 = (double)wv.w;
                double tv0 = t[0][b2][cbase + i];
                double tv1 = t[1][b2][cbase + i];
                acc[0][0] = fma(tv0, w0, acc[0][0]);
                acc[0][1] = fma(tv0, w1, acc[0][1]);
                acc[0][2] = fma(tv0, w2, acc[0][2]);
                acc[0][3] = fma(tv0, w3, acc[0][3]);
                acc[1][0] = fma(tv1, w0, acc[1][0]);
                acc[1][1] = fma(tv1, w1, acc[1][1]);
                acc[1][2] = fma(tv1, w2, acc[1][2]);
                acc[1][3] = fma(tv1, w3, acc[1][3]);
            }
        }
        __syncthreads();
    }
    for (int qi = 0; qi < nq; ++qi) {
        red[seg][o0 + 0] = acc[qi][0];
        red[seg][o0 + 1] = acc[qi][1];
        red[seg][o0 + 2] = acc[qi][2];
        red[seg][o0 + 3] = acc[qi][3];
        __syncthreads();
        if (tid < 64) {
            double v = 0.0;
#pragma unroll
            for (int s2 = 0; s2 < 16; ++s2) v += red[s2][tid];
            v += (double)bias[tid];
            fout[(size_t)(q0 + qi) * 64 + tid] = v > 0.0 ? v : 0.0;
        }
        __syncthreads();
    }
}

// Stage 1 (small Q): t[q-q0][45*C], grid (qcount, 5 basis chunks of 9).
__global__ __launch_bounds__(256) void t_kernel(
    const float *__restrict__ rrot, const int *__restrict__ idx, int k,
    const double *__restrict__ fin, int C, int q0, double *__restrict__ tbuf) {
    __shared__ double phi_sh[16][45];
    __shared__ int idx_sh[16];
    extern __shared__ double nf[];  // [16][C]
    int q = q0 + blockIdx.x;
    int bch = blockIdx.y * 9;
    int tid = threadIdx.x;
    if (tid < k) {
        idx_sh[tid] = idx[q * k + tid];
        double phi[45];
        compute_phi(rrot, q, tid, phi);
#pragma unroll
        for (int b2 = 0; b2 < 45; ++b2) phi_sh[tid][b2] = phi[b2];
    }
    __syncthreads();
    for (int e2 = tid; e2 < k * C; e2 += 256) {
        int j = e2 / C, cc = e2 - j * C;
        nf[j * C + cc] = fin[(size_t)idx_sh[j] * C + cc];
    }
    __syncthreads();
    int K = 45 * C;
    for (int e2 = tid; e2 < 9 * C; e2 += 256) {
        int b2 = bch + e2 / C, cc = e2 % C;
        double a2 = 0.0;
        for (int j = 0; j < k; ++j) a2 = fma(phi_sh[j][b2], nf[j * C + cc], a2);
        tbuf[(size_t)blockIdx.x * K + b2 * C + cc] = a2 / (double)k;
    }
}

// Stage 2: K-split GEMM, f64 atomics straight into acc (= fout region).
__global__ __launch_bounds__(256) void gemm_kernel(
    const double *__restrict__ tbuf, const float *__restrict__ W,
    int K, int O, int q0, int q1, int kchunk, double *__restrict__ acc) {
    int OT = O < 256 ? O : 256;
    int qpb = 256 / OT;
    int tid = threadIdx.x;
    int o = blockIdx.x * OT + (tid % OT);
    int q = q0 + blockIdx.y * qpb + tid / OT;
    if (q >= q1) return;
    int k0 = blockIdx.z * kchunk;
    int kend = min(k0 + kchunk, K);
    const double *tp = tbuf + (size_t)(q - q0) * K;
    const float *wp = W + (size_t)k0 * O + o;
    double a0 = 0.0, a1 = 0.0;
    int kk = k0;
    for (; kk + 2 <= kend; kk += 2) {
        a0 = fma(tp[kk], (double)wp[0], a0);
        a1 = fma(tp[kk + 1], (double)wp[O], a1);
        wp += 2 * (size_t)O;
    }
    if (kk < kend) a0 = fma(tp[kk], (double)wp[0], a0);
    atomicAdd(&acc[(size_t)q * O + o], a0 + a1);
}

// In-place: fout = relu(fout + bias)
__global__ void finalize_kernel(const float *__restrict__ bias,
                                int Q, int O, double *__restrict__ fout) {
    int i = blockIdx.x * 256 + threadIdx.x;
    if (i >= Q * O) return;
    int o = i % O;
    double v = fout[i] + (double)bias[o];
    fout[i] = v > 0.0 ? v : 0.0;
}

__global__ void resid0_kernel(const float *__restrict__ chanf, const float *__restrict__ p,
                              const double *__restrict__ x, double *__restrict__ fout) {
    int i = blockIdx.x * 256 + threadIdx.x;
    if (i >= 2435 * 64) return;
    int q = i >> 6, o = i & 63;
    const float *f = chanf + 4 * q;
    float c = fmaf(f[0], p[o], 0.0f);
    c = fmaf(f[1], p[64 + o], c);
    c = fmaf(f[2], p[128 + o], c);
    c = fmaf(f[3], p[192 + o], c);
    double v = x[i] + (double)c;
    fout[i] = v > 0.0 ? v : 0.0;
}

__global__ void resid64_kernel(const double *__restrict__ fin, int Cin,
                               const float *__restrict__ p, const double *__restrict__ x,
                               int Q, int Cout, double *__restrict__ fout) {
    int i = blockIdx.x * blockDim.x + threadIdx.x;
    if (i >= Q * Cout) return;
    int q = i / Cout, o = i - q * Cout;
    double acc = 0.0;
    for (int c = 0; c < Cin; ++c) acc = fma(fin[q * Cin + c], (double)p[c * Cout + o], acc);
    double v = x[i] + acc;
    fout[i] = v > 0.0 ? v : 0.0;
}

__global__ void head_kernel(const double *__restrict__ feat, const float *__restrict__ hw,
                            const float *__restrict__ hb, float *__restrict__ out) {
    if (threadIdx.x == 0 && blockIdx.x == 0) {
        double acc = 0.0;
        for (int c = 0; c < 512; ++c) acc = fma(feat[c], (double)hw[c], acc);
        out[0] = (float)(acc + (double)hb[0]);
    }
}

// ---------------------------------------------------------------------------

extern "C" void kernel_launch(void *const *d_in, const int *in_sizes, int n_in,
                              void *d_out, int out_size, void *d_ws, size_t ws_size,
                              hipStream_t stream) {
    (void)in_sizes; (void)n_in; (void)out_size;

    const float *posf = (const float *)d_in[0];
    const float *chanf = (const float *)d_in[1];
    const float *W[8], *B[8];
    for (int li = 1; li <= 7; ++li) {
        W[li] = (const float *)d_in[2 + 2 * (li - 1)];
        B[li] = (const float *)d_in[3 + 2 * (li - 1)];
    }
    const float *P[5];
    for (int bi = 1; bi <= 4; ++bi) P[bi] = (const float *)d_in[15 + bi];
    const float *hw = (const float *)d_in[20];
    const float *hb = (const float *)d_in[21];

    // workspace layout (bytes)
    char *wsb = (char *)d_ws;
    double *B1   = (double *)(wsb + 0);            // 2435*64 f64 = 1,246,720
    double *B2   = (double *)(wsb + 1246720);
    double *B3   = (double *)(wsb + 2493440);
    float *rrot  = (float *)(wsb + 3740160);       // 2435*48 f32 = 467,520
    int *idx     = (int *)(wsb + 4207680);         // 2435*16 = 155,840
    float4 *pos4 = (float4 *)(wsb + 4363520);      // 32768*16 = 524,288
    double *tbuf = (double *)(wsb + 4887808);      // 4 MB (small-Q chunks)
    if (ws_size < 9082112) return;

    prep_kernel<<<128, 256, 0, stream>>>(posf, pos4);

    auto knng = [&](int Q, int S, int k) {
        if (S <= 64)
            knngs_kernel<<<Q, 64, 0, stream>>>(pos4, posf, S, k, idx, rrot);
        else
            knng16_kernel<<<Q, 256, 0, stream>>>(pos4, posf, S, idx, rrot);
    };

    // fused per-query path (B0-L1)
    auto conv = [&](int Q, int S, int k, const double *fin64, const float *fin32, int C,
                    const float *w, const float *bias, int O, double *fout) {
        knng(Q, S, k);
        size_t dyn = (size_t)(16 + 9) * C * sizeof(double);
        feat_kernel<<<Q, 256, dyn, stream>>>(rrot, idx, k, fin64, fin32, C, w, bias, O, fout);
    };

    // specialized C=64/O=64 path (B0-L2)
    auto conv64 = [&](int Q, int S, const double *fin, const float *w,
                      const float *bias, double *fout) {
        knng(Q, S, 16);
        feat64_kernel<<<(Q + 1) / 2, 256, 0, stream>>>(rrot, idx, fin, w, bias, Q, fout);
    };

    // split t + K-parallel GEMM path (small Q) -- K-split grid is essential
    auto conv2 = [&](int Q, int S, int k, const double *fin, int C,
                     const float *w, const float *bias, int O, double *fout, int ksplit) {
        knng(Q, S, k);
        int K = 45 * C;
        hipMemsetAsync(fout, 0, (size_t)Q * O * sizeof(double), stream);
        int qc = 4194304 / (K * 8);
        if (qc > Q) qc = Q;
        int OT = O < 256 ? O : 256;
        int qpb = 256 / OT;
        int kchunk = (K + ksplit - 1) / ksplit;
        for (int q0 = 0; q0 < Q; q0 += qc) {
            int qn = min(qc, Q - q0);
            dim3 gt(qn, 5);
            t_kernel<<<gt, 256, (size_t)16 * C * sizeof(double), stream>>>(
                rrot, idx, k, fin, C, q0, tbuf);
            dim3 g(O / OT, (qn + qpb - 1) / qpb, ksplit);
            gemm_kernel<<<g, 256, 0, stream>>>(tbuf, w, K, O, q0, q0 + qn, kchunk, fout);
        }
        finalize_kernel<<<(Q * O + 255) / 256, 256, 0, stream>>>(bias, Q, O, fout);
    };

    // Block 0 (Q=2435)
    conv(2435, 32768, 16, nullptr, chanf, 4, W[1], B[1], 64, B1);
    conv64(2435, 2435, B1, W[2], B[2], B2);
    resid0_kernel<<<(2435 * 64 + 255) / 256, 256, 0, stream>>>(chanf, P[1], B2, B3);
    // Block 1 (Q=181)
    conv2(181, 2435, 16, B3, 64, W[3], B[3], 128, B1, 6);
    conv2(181, 181, 16, B1, 128, W[4], B[4], 128, B2, 8);
    resid64_kernel<<<(181 * 128 + 255) / 256, 256, 0, stream>>>(B3, 64, P[2], B2, 181, 128, B1);
    // Block 2 (Q=13)
    conv2(13, 181, 16, B1, 128, W[5], B[5], 256, B2, 40);
    conv2(13, 13, 13, B2, 256, W[6], B[6], 256, B3, 48);
    resid64_kernel<<<(13 * 256 + 255) / 256, 256, 0, stream>>>(B1, 128, P[3], B3, 13, 256, B2);
    // Block 3 (Q=1)
    conv2(1, 13, 13, B2, 256, W[7], B[7], 512, B1, 128);
    resid64_kernel<<<(1 * 512 + 255) / 256, 256, 0, stream>>>(B2, 256, P[4], B1, 1, 512, B3);

    head_kernel<<<1, 64, 0, stream>>>(B3, hw, hb, (float *)d_out);
}